// Round 5
// baseline (111.542 us; speedup 1.0000x reference)
//
#include <hip/hip_runtime.h>
#include <math.h>

#define DEPTH 15
#define N_LEAVES (1 << DEPTH)        // 32768
#define N_NODES (2 * N_LEAVES - 1)   // 65535
#define FDIM 256
#define CDIM 2
#define ROWF (FDIM * CDIM)           // 512 floats per node row
#define LPW 4                        // leaves per wave
#define NBLOCKS 2048                 // 8192 waves x 4 leaves = 32768 leaves
#define N_AUX 8191                   // nodes at levels 0..12 (shared rows)
#define MIN_DIST 1e-7f

__device__ __forceinline__ void load_row(const float* __restrict__ deltas, int node, int lane,
                                         float4& d0, float4& d1) {
    const float* p = deltas + (size_t)node * ROWF + (lane << 3);
    d0 = *(const float4*)p;        // (f0,c0)(f0,c1)(f1,c0)(f1,c1)
    d1 = *(const float4*)(p + 4);  // (f2,c0)(f2,c1)(f3,c0)(f3,c1)
}

template <int S, int N>
__device__ __forceinline__ void fma_node(const float4 (&xf)[LPW], const float4& d0, const float4& d1,
                                         float (&a0)[LPW], float (&a1)[LPW]) {
#pragma unroll
    for (int i = S; i < S + N; ++i) {
        a0[i] += xf[i].x * d0.x + xf[i].y * d0.z + xf[i].z * d1.x + xf[i].w * d1.z;
        a1[i] += xf[i].x * d0.y + xf[i].y * d0.w + xf[i].z * d1.y + xf[i].w * d1.w;
    }
}

__device__ __forceinline__ float abs8(const float4& d0, const float4& d1) {
    return fabsf(d0.x) + fabsf(d0.y) + fabsf(d0.z) + fabsf(d0.w)
         + fabsf(d1.x) + fabsf(d1.y) + fabsf(d1.z) + fabsf(d1.w);
}

__device__ __forceinline__ float sq8(const float4& d0, const float4& d1) {
    return d0.x * d0.x + d0.y * d0.y + d0.z * d0.z + d0.w * d0.w
         + d1.x * d1.x + d1.y * d1.y + d1.z * d1.z + d1.w * d1.w;
}

// No occupancy demand in launch_bounds: rounds 2/3 showed any forced wave
// minimum drives the allocator below ~100 VGPR and spills 150-400 MB to
// scratch, which also evicts the L3-resident input set.
__global__ __launch_bounds__(256) void tree_main(const float* __restrict__ x,
                                                 const float* __restrict__ deltas,
                                                 const float* __restrict__ bl,
                                                 float* __restrict__ out,
                                                 float* __restrict__ ws,
                                                 unsigned* __restrict__ cnt) {
    // XCD-aware bijective swizzle (2048 % 8 == 0): each XCD owns a
    // contiguous 4096-leaf subtree -> upper-level rows stay in its L2.
    int bid = (int)blockIdx.x;
    int swz = (bid & 7) * (NBLOCKS / 8) + (bid >> 3);

    int wv = (int)threadIdx.x >> 6;        // wave in block, 0..3
    int lane = (int)threadIdx.x & 63;
    int wave = swz * 4 + wv;               // logical wave id, 0..8191
    int leaf0 = wave * LPW;

    // x fragments: lane owns features [4*lane, 4*lane+4) for 4 leaves
    float4 xf[LPW];
#pragma unroll
    for (int i = 0; i < LPW; ++i)
        xf[i] = *(const float4*)(x + (size_t)(leaf0 + i) * FDIM + (lane << 2));

    float acc0[LPW] = {0.f, 0.f, 0.f, 0.f};
    float acc1[LPW] = {0.f, 0.f, 0.f, 0.f};
    float reg = 0.f;

    // ---- Batch 0: levels 0..4 (shared rows) — 10 loads in flight ----
    {
        float4 d0[5], d1[5];
#pragma unroll
        for (int l = 0; l < 5; ++l) {
            int node = ((1 << l) - 1) + (leaf0 >> (DEPTH - l));
            load_row(deltas, node, lane, d0[l], d1[l]);
        }
#pragma unroll
        for (int l = 0; l < 5; ++l)
            fma_node<0, 4>(xf, d0[l], d1[l], acc0, acc1);
    }

    // ---- Batch 1: levels 5..9 (shared rows) ----
    {
        float4 d0[5], d1[5];
#pragma unroll
        for (int l = 0; l < 5; ++l) {
            int lev = l + 5;
            int node = ((1 << lev) - 1) + (leaf0 >> (DEPTH - lev));
            load_row(deltas, node, lane, d0[l], d1[l]);
        }
#pragma unroll
        for (int l = 0; l < 5; ++l)
            fma_node<0, 4>(xf, d0[l], d1[l], acc0, acc1);
    }

    // ---- Batch 2: levels 10..12 (shared) + level 13 (owned, 4 leaves) ----
    {
        float4 d0[4], d1[4];
#pragma unroll
        for (int l = 0; l < 3; ++l) {
            int lev = l + 10;
            int node = ((1 << lev) - 1) + (leaf0 >> (DEPTH - lev));
            load_row(deltas, node, lane, d0[l], d1[l]);
        }
        int n13 = ((1 << 13) - 1) + (leaf0 >> 2);
        load_row(deltas, n13, lane, d0[3], d1[3]);
        float dist13 = fmaxf(bl[n13 - 1], MIN_DIST);
#pragma unroll
        for (int l = 0; l < 4; ++l)
            fma_node<0, 4>(xf, d0[l], d1[l], acc0, acc1);
        reg += abs8(d0[3], d1[3]) / dist13;
    }

    // ---- Batch 3: level 14 x2 + level 15 x4 (owned) + aux shared-node ----
    {
        float4 d0[7], d1[7];
        int n14 = ((1 << 14) - 1) + (leaf0 >> 1);
        int n15 = ((1 << 15) - 1) + leaf0;
        int a = min(wave, N_AUX - 1);          // aux node, clamped for wave 8191
        load_row(deltas, n14 + 0, lane, d0[0], d1[0]);
        load_row(deltas, n14 + 1, lane, d0[1], d1[1]);
        load_row(deltas, n15 + 0, lane, d0[2], d1[2]);
        load_row(deltas, n15 + 1, lane, d0[3], d1[3]);
        load_row(deltas, n15 + 2, lane, d0[4], d1[4]);
        load_row(deltas, n15 + 3, lane, d0[5], d1[5]);
        load_row(deltas, a, lane, d0[6], d1[6]);

        float dist14a = fmaxf(bl[n14 - 1], MIN_DIST);
        float dist14b = fmaxf(bl[n14 + 0], MIN_DIST);
        float dist15a = fmaxf(bl[n15 - 1], MIN_DIST);
        float dist15b = fmaxf(bl[n15 + 0], MIN_DIST);
        float dist15c = fmaxf(bl[n15 + 1], MIN_DIST);
        float dist15d = fmaxf(bl[n15 + 2], MIN_DIST);
        float distaux = fmaxf(bl[max(a - 1, 0)], MIN_DIST);  // a==0 -> unused

        fma_node<0, 2>(xf, d0[0], d1[0], acc0, acc1);
        fma_node<2, 2>(xf, d0[1], d1[1], acc0, acc1);
        fma_node<0, 1>(xf, d0[2], d1[2], acc0, acc1);
        fma_node<1, 1>(xf, d0[3], d1[3], acc0, acc1);
        fma_node<2, 1>(xf, d0[4], d1[4], acc0, acc1);
        fma_node<3, 1>(xf, d0[5], d1[5], acc0, acc1);

        reg += abs8(d0[0], d1[0]) / dist14a;
        reg += abs8(d0[1], d1[1]) / dist14b;
        reg += abs8(d0[2], d1[2]) / dist15a;
        reg += abs8(d0[3], d1[3]) / dist15b;
        reg += abs8(d0[4], d1[4]) / dist15c;
        reg += abs8(d0[5], d1[5]) / dist15d;

        float vaux = (a == 0) ? sq8(d0[6], d1[6])
                              : abs8(d0[6], d1[6]) / distaux;
        reg += (wave < N_AUX) ? vaux : 0.f;
    }

    // Butterfly-reduce logits across the wave
#pragma unroll
    for (int i = 0; i < LPW; ++i) {
#pragma unroll
        for (int m = 1; m < 64; m <<= 1) {
            acc0[i] += __shfl_xor(acc0[i], m, 64);
            acc1[i] += __shfl_xor(acc1[i], m, 64);
        }
    }

    // Move leaf i's logits to lane i (static cndmask chain), then one
    // coalesced float2 store per wave (lanes 0..3 active).
    float v0 = acc0[0], v1 = acc1[0];
#pragma unroll
    for (int i = 1; i < LPW; ++i) {
        bool sel = (lane == i);
        v0 = sel ? acc0[i] : v0;
        v1 = sel ? acc1[i] : v1;
    }
    {
        float m = fmaxf(v0, v1);
        float e0 = __expf(v0 - m);
        float e1 = __expf(v1 - m);
        float inv = 1.f / (e0 + e1);
        if (lane < LPW)
            *(float2*)(out + (size_t)(leaf0 + lane) * CDIM) = make_float2(e0 * inv, e1 * inv);
    }

    // Regularizer: wave butterfly -> per-block LDS -> one ws partial/block,
    // then last-block-done fused final reduce (no second kernel launch).
#pragma unroll
    for (int m = 1; m < 64; m <<= 1) reg += __shfl_xor(reg, m, 64);

    __shared__ float part[4];
    __shared__ int is_last;
    if (lane == 0) part[wv] = reg;
    __syncthreads();
    if (threadIdx.x == 0) {
        float blocksum = part[0] + part[1] + part[2] + part[3];
        // agent-scope release store: visible to the acquiring last block
        // across non-coherent per-XCD L2s.
        __hip_atomic_store(&ws[swz], blocksum, __ATOMIC_RELEASE, __HIP_MEMORY_SCOPE_AGENT);
        unsigned old = __hip_atomic_fetch_add(cnt, 1u, __ATOMIC_ACQ_REL, __HIP_MEMORY_SCOPE_AGENT);
        is_last = (old == NBLOCKS - 1) ? 1 : 0;
    }
    __syncthreads();

    if (is_last) {   // block-uniform branch: __syncthreads inside is legal
        float s = 0.f;
#pragma unroll
        for (int j = 0; j < NBLOCKS / 256; ++j) {
            int i = (int)threadIdx.x + j * 256;
            s += __hip_atomic_load(&ws[i], __ATOMIC_ACQUIRE, __HIP_MEMORY_SCOPE_AGENT);
        }
#pragma unroll
        for (int m = 1; m < 64; m <<= 1) s += __shfl_xor(s, m, 64);
        __shared__ float p2[4];
        if (lane == 0) p2[wv] = s;
        __syncthreads();
        if (threadIdx.x == 0)
            out[(size_t)N_LEAVES * CDIM] = p2[0] + p2[1] + p2[2] + p2[3];
    }
}

extern "C" void kernel_launch(void* const* d_in, const int* in_sizes, int n_in,
                              void* d_out, int out_size, void* d_ws, size_t ws_size,
                              hipStream_t stream) {
    const float* x      = (const float*)d_in[0];
    const float* deltas = (const float*)d_in[1];
    const float* bl     = (const float*)d_in[2];
    float* out = (float*)d_out;
    float* ws  = (float*)d_ws;                       // 2048 partials
    unsigned* cnt = (unsigned*)(ws + NBLOCKS);       // +1 counter word

    // Counter must start at 0 every call (ws is poisoned once, not per-replay;
    // last-block detection needs old == NBLOCKS-1 exactly).
    hipMemsetAsync(cnt, 0, sizeof(unsigned), stream);

    tree_main<<<NBLOCKS, 256, 0, stream>>>(x, deltas, bl, out, ws, cnt);
}

// Round 6
// 47.820 us; speedup vs baseline: 2.3325x; 2.3325x over previous
//
#include <hip/hip_runtime.h>
#include <math.h>

#define DEPTH 15
#define N_LEAVES (1 << DEPTH)        // 32768
#define N_NODES (2 * N_LEAVES - 1)   // 65535
#define FDIM 256
#define CDIM 2
#define ROWF (FDIM * CDIM)           // 512 floats per node row
#define LPW 4                        // leaves per wave
#define NBLOCKS 2048                 // 8192 waves x 4 leaves = 32768 leaves
#define N_AUX 8191                   // nodes at levels 0..12 (shared rows)
#define MIN_DIST 1e-7f

__device__ __forceinline__ void load_row(const float* __restrict__ deltas, int node, int lane,
                                         float4& d0, float4& d1) {
    const float* p = deltas + (size_t)node * ROWF + (lane << 3);
    d0 = *(const float4*)p;        // (f0,c0)(f0,c1)(f1,c0)(f1,c1)
    d1 = *(const float4*)(p + 4);  // (f2,c0)(f2,c1)(f3,c0)(f3,c1)
}

template <int S, int N>
__device__ __forceinline__ void fma_node(const float4 (&xf)[LPW], const float4& d0, const float4& d1,
                                         float (&a0)[LPW], float (&a1)[LPW]) {
#pragma unroll
    for (int i = S; i < S + N; ++i) {
        a0[i] += xf[i].x * d0.x + xf[i].y * d0.z + xf[i].z * d1.x + xf[i].w * d1.z;
        a1[i] += xf[i].x * d0.y + xf[i].y * d0.w + xf[i].z * d1.y + xf[i].w * d1.w;
    }
}

__device__ __forceinline__ float abs8(const float4& d0, const float4& d1) {
    return fabsf(d0.x) + fabsf(d0.y) + fabsf(d0.z) + fabsf(d0.w)
         + fabsf(d1.x) + fabsf(d1.y) + fabsf(d1.z) + fabsf(d1.w);
}

__device__ __forceinline__ float sq8(const float4& d0, const float4& d1) {
    return d0.x * d0.x + d0.y * d0.y + d0.z * d0.z + d0.w * d0.w
         + d1.x * d1.x + d1.y * d1.y + d1.z * d1.z + d1.w * d1.w;
}

// No occupancy demand in launch_bounds (rounds 2/3: forced wave minimums
// spill 150-400 MB to scratch). No fenced atomics (round 5: agent-scope
// acq_rel per block wipes L1/L2 for running blocks, 3x regression).
__global__ __launch_bounds__(256) void tree_main(const float* __restrict__ x,
                                                 const float* __restrict__ deltas,
                                                 const float* __restrict__ bl,
                                                 float* __restrict__ out) {
    // XCD-aware bijective swizzle (2048 % 8 == 0): each XCD owns a
    // contiguous 4096-leaf subtree -> upper-level rows stay in its L2.
    int bid = (int)blockIdx.x;
    int swz = (bid & 7) * (NBLOCKS / 8) + (bid >> 3);

    int wv = (int)threadIdx.x >> 6;        // wave in block, 0..3
    int lane = (int)threadIdx.x & 63;
    int wave = swz * 4 + wv;               // logical wave id, 0..8191
    int leaf0 = wave * LPW;

    // x fragments: lane owns features [4*lane, 4*lane+4) for 4 leaves
    float4 xf[LPW];
#pragma unroll
    for (int i = 0; i < LPW; ++i)
        xf[i] = *(const float4*)(x + (size_t)(leaf0 + i) * FDIM + (lane << 2));

    float acc0[LPW] = {0.f, 0.f, 0.f, 0.f};
    float acc1[LPW] = {0.f, 0.f, 0.f, 0.f};
    float reg = 0.f;

    // ---- Batch 0: levels 0..4 (shared rows) — 10 loads in flight ----
    {
        float4 d0[5], d1[5];
#pragma unroll
        for (int l = 0; l < 5; ++l) {
            int node = ((1 << l) - 1) + (leaf0 >> (DEPTH - l));
            load_row(deltas, node, lane, d0[l], d1[l]);
        }
#pragma unroll
        for (int l = 0; l < 5; ++l)
            fma_node<0, 4>(xf, d0[l], d1[l], acc0, acc1);
    }

    // ---- Batch 1: levels 5..9 (shared rows) ----
    {
        float4 d0[5], d1[5];
#pragma unroll
        for (int l = 0; l < 5; ++l) {
            int lev = l + 5;
            int node = ((1 << lev) - 1) + (leaf0 >> (DEPTH - lev));
            load_row(deltas, node, lane, d0[l], d1[l]);
        }
#pragma unroll
        for (int l = 0; l < 5; ++l)
            fma_node<0, 4>(xf, d0[l], d1[l], acc0, acc1);
    }

    // ---- Batch 2: levels 10..12 (shared) + level 13 (owned, 4 leaves) ----
    {
        float4 d0[4], d1[4];
#pragma unroll
        for (int l = 0; l < 3; ++l) {
            int lev = l + 10;
            int node = ((1 << lev) - 1) + (leaf0 >> (DEPTH - lev));
            load_row(deltas, node, lane, d0[l], d1[l]);
        }
        int n13 = ((1 << 13) - 1) + (leaf0 >> 2);
        load_row(deltas, n13, lane, d0[3], d1[3]);
        float dist13 = fmaxf(bl[n13 - 1], MIN_DIST);
#pragma unroll
        for (int l = 0; l < 4; ++l)
            fma_node<0, 4>(xf, d0[l], d1[l], acc0, acc1);
        reg += abs8(d0[3], d1[3]) / dist13;
    }

    // ---- Batch 3: level 14 x2 + level 15 x4 (owned) + aux shared-node ----
    {
        float4 d0[7], d1[7];
        int n14 = ((1 << 14) - 1) + (leaf0 >> 1);
        int n15 = ((1 << 15) - 1) + leaf0;
        int a = min(wave, N_AUX - 1);          // aux node, clamped for wave 8191
        load_row(deltas, n14 + 0, lane, d0[0], d1[0]);
        load_row(deltas, n14 + 1, lane, d0[1], d1[1]);
        load_row(deltas, n15 + 0, lane, d0[2], d1[2]);
        load_row(deltas, n15 + 1, lane, d0[3], d1[3]);
        load_row(deltas, n15 + 2, lane, d0[4], d1[4]);
        load_row(deltas, n15 + 3, lane, d0[5], d1[5]);
        load_row(deltas, a, lane, d0[6], d1[6]);

        float dist14a = fmaxf(bl[n14 - 1], MIN_DIST);
        float dist14b = fmaxf(bl[n14 + 0], MIN_DIST);
        float dist15a = fmaxf(bl[n15 - 1], MIN_DIST);
        float dist15b = fmaxf(bl[n15 + 0], MIN_DIST);
        float dist15c = fmaxf(bl[n15 + 1], MIN_DIST);
        float dist15d = fmaxf(bl[n15 + 2], MIN_DIST);
        float distaux = fmaxf(bl[max(a - 1, 0)], MIN_DIST);  // a==0 -> unused

        fma_node<0, 2>(xf, d0[0], d1[0], acc0, acc1);
        fma_node<2, 2>(xf, d0[1], d1[1], acc0, acc1);
        fma_node<0, 1>(xf, d0[2], d1[2], acc0, acc1);
        fma_node<1, 1>(xf, d0[3], d1[3], acc0, acc1);
        fma_node<2, 1>(xf, d0[4], d1[4], acc0, acc1);
        fma_node<3, 1>(xf, d0[5], d1[5], acc0, acc1);

        reg += abs8(d0[0], d1[0]) / dist14a;
        reg += abs8(d0[1], d1[1]) / dist14b;
        reg += abs8(d0[2], d1[2]) / dist15a;
        reg += abs8(d0[3], d1[3]) / dist15b;
        reg += abs8(d0[4], d1[4]) / dist15c;
        reg += abs8(d0[5], d1[5]) / dist15d;

        float vaux = (a == 0) ? sq8(d0[6], d1[6])
                              : abs8(d0[6], d1[6]) / distaux;
        reg += (wave < N_AUX) ? vaux : 0.f;
    }

    // Butterfly-reduce logits across the wave
#pragma unroll
    for (int i = 0; i < LPW; ++i) {
#pragma unroll
        for (int m = 1; m < 64; m <<= 1) {
            acc0[i] += __shfl_xor(acc0[i], m, 64);
            acc1[i] += __shfl_xor(acc1[i], m, 64);
        }
    }

    // Move leaf i's logits to lane i (static cndmask chain), then one
    // coalesced float2 store per wave (lanes 0..3 active).
    float v0 = acc0[0], v1 = acc1[0];
#pragma unroll
    for (int i = 1; i < LPW; ++i) {
        bool sel = (lane == i);
        v0 = sel ? acc0[i] : v0;
        v1 = sel ? acc1[i] : v1;
    }
    {
        float m = fmaxf(v0, v1);
        float e0 = __expf(v0 - m);
        float e1 = __expf(v1 - m);
        float inv = 1.f / (e0 + e1);
        if (lane < LPW)
            *(float2*)(out + (size_t)(leaf0 + lane) * CDIM) = make_float2(e0 * inv, e1 * inv);
    }

    // Regularizer: wave butterfly -> per-block LDS -> ONE relaxed atomicAdd
    // per block (global_atomic_add_f32, no cache-maintenance ops; 2048 adds
    // spread over the kernel lifetime -> negligible serialization tail).
#pragma unroll
    for (int m = 1; m < 64; m <<= 1) reg += __shfl_xor(reg, m, 64);

    __shared__ float part[4];
    if (lane == 0) part[wv] = reg;
    __syncthreads();
    if (threadIdx.x == 0)
        atomicAdd(out + (size_t)N_LEAVES * CDIM, part[0] + part[1] + part[2] + part[3]);
}

extern "C" void kernel_launch(void* const* d_in, const int* in_sizes, int n_in,
                              void* d_out, int out_size, void* d_ws, size_t ws_size,
                              hipStream_t stream) {
    const float* x      = (const float*)d_in[0];
    const float* deltas = (const float*)d_in[1];
    const float* bl     = (const float*)d_in[2];
    float* out = (float*)d_out;

    // Zero the scalar accumulator each call (graph-capture-safe async memset).
    hipMemsetAsync(out + (size_t)N_LEAVES * CDIM, 0, sizeof(float), stream);

    tree_main<<<NBLOCKS, 256, 0, stream>>>(x, deltas, bl, out);
}

// Round 7
// 38.059 us; speedup vs baseline: 2.9308x; 1.2565x over previous
//
#include <hip/hip_runtime.h>
#include <math.h>

#define DEPTH 15
#define N_LEAVES (1 << DEPTH)        // 32768
#define N_NODES (2 * N_LEAVES - 1)   // 65535
#define FDIM 256
#define CDIM 2
#define ROWF (FDIM * CDIM)           // 512 floats per node row
#define LPW 4                        // leaves per wave
#define NBLOCKS 2048                 // 8192 waves x 4 leaves = 32768 leaves
#define N_AUX 8191                   // nodes at levels 0..12 (shared rows)
#define MIN_DIST 1e-7f

__device__ __forceinline__ void load_row(const float* __restrict__ deltas, int node, int lane,
                                         float4& d0, float4& d1) {
    const float* p = deltas + (size_t)node * ROWF + (lane << 3);
    d0 = *(const float4*)p;        // (f0,c0)(f0,c1)(f1,c0)(f1,c1)
    d1 = *(const float4*)(p + 4);  // (f2,c0)(f2,c1)(f3,c0)(f3,c1)
}

template <int S, int N>
__device__ __forceinline__ void fma_node(const float4 (&xf)[LPW], const float4& d0, const float4& d1,
                                         float (&a0)[LPW], float (&a1)[LPW]) {
#pragma unroll
    for (int i = S; i < S + N; ++i) {
        a0[i] += xf[i].x * d0.x + xf[i].y * d0.z + xf[i].z * d1.x + xf[i].w * d1.z;
        a1[i] += xf[i].x * d0.y + xf[i].y * d0.w + xf[i].z * d1.y + xf[i].w * d1.w;
    }
}

__device__ __forceinline__ float abs8(const float4& d0, const float4& d1) {
    return fabsf(d0.x) + fabsf(d0.y) + fabsf(d0.z) + fabsf(d0.w)
         + fabsf(d1.x) + fabsf(d1.y) + fabsf(d1.z) + fabsf(d1.w);
}

__device__ __forceinline__ float sq8(const float4& d0, const float4& d1) {
    return d0.x * d0.x + d0.y * d0.y + d0.z * d0.z + d0.w * d0.w
         + d1.x * d1.x + d1.y * d1.y + d1.z * d1.z + d1.w * d1.w;
}

// No occupancy demand in launch_bounds (rounds 2/3: forced wave minimums
// spill 150-400 MB to scratch). No atomics/fences in the epilogue (round 5:
// agent-scope acq_rel wipes caches, 3x; round 6: completion-clustered
// same-address atomicAdds add ~+9us tail).
__global__ __launch_bounds__(256) void tree_main(const float* __restrict__ x,
                                                 const float* __restrict__ deltas,
                                                 const float* __restrict__ bl,
                                                 float* __restrict__ out,
                                                 float* __restrict__ ws) {
    // XCD-aware bijective swizzle (2048 % 8 == 0): each XCD owns a
    // contiguous 4096-leaf subtree -> upper-level rows stay in its L2.
    int bid = (int)blockIdx.x;
    int swz = (bid & 7) * (NBLOCKS / 8) + (bid >> 3);

    int wv = (int)threadIdx.x >> 6;        // wave in block, 0..3
    int lane = (int)threadIdx.x & 63;
    int wave = swz * 4 + wv;               // logical wave id, 0..8191
    int leaf0 = wave * LPW;

    // x fragments: lane owns features [4*lane, 4*lane+4) for 4 leaves
    float4 xf[LPW];
#pragma unroll
    for (int i = 0; i < LPW; ++i)
        xf[i] = *(const float4*)(x + (size_t)(leaf0 + i) * FDIM + (lane << 2));

    float acc0[LPW] = {0.f, 0.f, 0.f, 0.f};
    float acc1[LPW] = {0.f, 0.f, 0.f, 0.f};
    float reg = 0.f;

    // Node indices (all wave-uniform -> scalar address math)
    int n13 = ((1 << 13) - 1) + (leaf0 >> 2);
    int n14 = ((1 << 14) - 1) + (leaf0 >> 1);
    int n15 = ((1 << 15) - 1) + leaf0;
    int a   = min(wave, N_AUX - 1);        // aux node (levels 0..12), clamped

    // ---------------- software pipeline: always ~10 loads in flight --------
    // Bank A: levels 0..4
    float4 a0[5], a1[5];
#pragma unroll
    for (int l = 0; l < 5; ++l) {
        int node = ((1 << l) - 1) + (leaf0 >> (DEPTH - l));
        load_row(deltas, node, lane, a0[l], a1[l]);
    }
    // Bank B: levels 5..9 (issued before consuming A)
    float4 b0[5], b1[5];
#pragma unroll
    for (int l = 0; l < 5; ++l) {
        int lev = l + 5;
        int node = ((1 << lev) - 1) + (leaf0 >> (DEPTH - lev));
        load_row(deltas, node, lane, b0[l], b1[l]);
    }

    // Consume A
#pragma unroll
    for (int l = 0; l < 5; ++l)
        fma_node<0, 4>(xf, a0[l], a1[l], acc0, acc1);

    // Bank C: levels 10..12 + n13 + aux (issued before consuming B)
    float4 c0[5], c1[5];
#pragma unroll
    for (int l = 0; l < 3; ++l) {
        int lev = l + 10;
        int node = ((1 << lev) - 1) + (leaf0 >> (DEPTH - lev));
        load_row(deltas, node, lane, c0[l], c1[l]);
    }
    load_row(deltas, n13, lane, c0[3], c1[3]);
    load_row(deltas, a,   lane, c0[4], c1[4]);
    float dist13  = fmaxf(bl[n13 - 1], MIN_DIST);
    float distaux = fmaxf(bl[max(a - 1, 0)], MIN_DIST);  // a==0 -> unused

    // Consume B
#pragma unroll
    for (int l = 0; l < 5; ++l)
        fma_node<0, 4>(xf, b0[l], b1[l], acc0, acc1);

    // Bank D: n14 x2 + n15 x4 (issued before consuming C)
    float4 e0[6], e1[6];
    load_row(deltas, n14 + 0, lane, e0[0], e1[0]);
    load_row(deltas, n14 + 1, lane, e0[1], e1[1]);
    load_row(deltas, n15 + 0, lane, e0[2], e1[2]);
    load_row(deltas, n15 + 1, lane, e0[3], e1[3]);
    load_row(deltas, n15 + 2, lane, e0[4], e1[4]);
    load_row(deltas, n15 + 3, lane, e0[5], e1[5]);
    float dist14a = fmaxf(bl[n14 - 1], MIN_DIST);
    float dist14b = fmaxf(bl[n14 + 0], MIN_DIST);
    float dist15a = fmaxf(bl[n15 - 1], MIN_DIST);
    float dist15b = fmaxf(bl[n15 + 0], MIN_DIST);
    float dist15c = fmaxf(bl[n15 + 1], MIN_DIST);
    float dist15d = fmaxf(bl[n15 + 2], MIN_DIST);

    // Consume C (levels 10..12 shared; n13 owned; aux reg node)
#pragma unroll
    for (int l = 0; l < 4; ++l)
        fma_node<0, 4>(xf, c0[l], c1[l], acc0, acc1);
    reg += abs8(c0[3], c1[3]) / dist13;
    {
        float vaux = (a == 0) ? sq8(c0[4], c1[4])
                              : abs8(c0[4], c1[4]) / distaux;
        reg += (wave < N_AUX) ? vaux : 0.f;
    }

    // Consume D (n14: 2 leaves each; n15: 1 leaf each; all owned)
    fma_node<0, 2>(xf, e0[0], e1[0], acc0, acc1);
    fma_node<2, 2>(xf, e0[1], e1[1], acc0, acc1);
    fma_node<0, 1>(xf, e0[2], e1[2], acc0, acc1);
    fma_node<1, 1>(xf, e0[3], e1[3], acc0, acc1);
    fma_node<2, 1>(xf, e0[4], e1[4], acc0, acc1);
    fma_node<3, 1>(xf, e0[5], e1[5], acc0, acc1);

    reg += abs8(e0[0], e1[0]) / dist14a;
    reg += abs8(e0[1], e1[1]) / dist14b;
    reg += abs8(e0[2], e1[2]) / dist15a;
    reg += abs8(e0[3], e1[3]) / dist15b;
    reg += abs8(e0[4], e1[4]) / dist15c;
    reg += abs8(e0[5], e1[5]) / dist15d;

    // Butterfly-reduce logits across the wave
#pragma unroll
    for (int i = 0; i < LPW; ++i) {
#pragma unroll
        for (int m = 1; m < 64; m <<= 1) {
            acc0[i] += __shfl_xor(acc0[i], m, 64);
            acc1[i] += __shfl_xor(acc1[i], m, 64);
        }
    }

    // Move leaf i's logits to lane i (static cndmask chain), then one
    // coalesced float2 store per wave (lanes 0..3 active).
    float v0 = acc0[0], v1 = acc1[0];
#pragma unroll
    for (int i = 1; i < LPW; ++i) {
        bool sel = (lane == i);
        v0 = sel ? acc0[i] : v0;
        v1 = sel ? acc1[i] : v1;
    }
    {
        float m = fmaxf(v0, v1);
        float e0s = __expf(v0 - m);
        float e1s = __expf(v1 - m);
        float inv = 1.f / (e0s + e1s);
        if (lane < LPW)
            *(float2*)(out + (size_t)(leaf0 + lane) * CDIM) = make_float2(e0s * inv, e1s * inv);
    }

    // Regularizer: wave butterfly -> per-block LDS -> one ws slot per block.
#pragma unroll
    for (int m = 1; m < 64; m <<= 1) reg += __shfl_xor(reg, m, 64);

    __shared__ float part[4];
    if (lane == 0) part[wv] = reg;
    __syncthreads();
    if (threadIdx.x == 0)
        ws[swz] = part[0] + part[1] + part[2] + part[3];
}

// Deterministic final reduce of 2048 per-block partials -> out[65536].
__global__ __launch_bounds__(256) void final_reduce(const float* __restrict__ ws,
                                                    float* __restrict__ out) {
    int lane = (int)threadIdx.x & 63;
    int wv = (int)threadIdx.x >> 6;
    float s = 0.f;
#pragma unroll
    for (int j = 0; j < NBLOCKS / 256; ++j)
        s += ws[(int)threadIdx.x + j * 256];
#pragma unroll
    for (int m = 1; m < 64; m <<= 1) s += __shfl_xor(s, m, 64);
    __shared__ float p[4];
    if (lane == 0) p[wv] = s;
    __syncthreads();
    if (threadIdx.x == 0)
        out[(size_t)N_LEAVES * CDIM] = p[0] + p[1] + p[2] + p[3];
}

extern "C" void kernel_launch(void* const* d_in, const int* in_sizes, int n_in,
                              void* d_out, int out_size, void* d_ws, size_t ws_size,
                              hipStream_t stream) {
    const float* x      = (const float*)d_in[0];
    const float* deltas = (const float*)d_in[1];
    const float* bl     = (const float*)d_in[2];
    float* out = (float*)d_out;
    float* ws  = (float*)d_ws;

    tree_main<<<NBLOCKS, 256, 0, stream>>>(x, deltas, bl, out, ws);
    final_reduce<<<1, 256, 0, stream>>>(ws, out);
}